// Round 15
// baseline (138.053 us; speedup 1.0000x reference)
//
#include <hip/hip_runtime.h>

// Karplus-Strong waveguide — TWO-KERNEL fully parallel solve.
//   Validated (r1-r14): out[t] = Σ_{k=0..199} A^k (D_l + D_r)[t],
//     A = g Z^{2L} e,  e = c⊛d (4 taps, Σe = 1),  g = gb·gn.
//   Exact factorization (each k=0..199 exactly once):
//     out = (Σ_{k<20} A^k) · (Σ_{j<10} A^{20j}) Ds
//   K1: Σ_{k<20} A^k Ds  — Ds staged from exc on the fly; filters ẽ^k = g^k e^k
//       built in-block (seed ẽ=g·e, conv tree, gains auto-fold).
//   K2: Σ_{j<10} A^{20j} — 9 filters ẽ^{20j} truncated to mu±5σ (e positive,
//       Σe=1 ⇒ Gaussian; analytic mu,σ), built in-block by ẽ20-chain.
// FIR inner loop: float2-rolling, 2×ds_read_b64 (window) + 1×ds_read_b128
// (filter, broadcast) per 8 FMAs; all LDS patterns 2-way/broadcast (free).

#define TPB   256
#define SAMP  2
#define CH    (TPB*SAMP)            // 512
#define LMAX  256
#define DSPAN (CH + 19*2*LMAX + 64) // 10304 floats
#define K1NF  19
#define K1STR 96                    // slot: 32 front pad + 64 data
#define K2NF  9
#define ROW2  (CH + 152 + 8)        // 672 floats per window row
#define ESTR  96                    // ẽ slots: 32 front + 64 data
#define SSTR  256                   // s slots: 64 front + 192 data

struct Base {
    int L, nUp, nDown;
    float gb, gn, g;
    float c0, c1, c2, d0, d1;
    float e[4];
};

static __device__ __forceinline__ Base mkbase(const int* Lp, const float* pk,
        const float* gnp, const float* gbp, const float* bbp, const float* dap) {
    Base b;
    b.L = Lp[0];
    b.gn = gnp[0]; b.gb = gbp[0];
    const float bb = bbp[0], da = dap[0];
    b.nUp   = (int)rintf((float)b.L * pk[0]);   // round-half-even == jnp.round
    b.nDown = b.L - b.nUp;
    b.c0 = da * (1.f - bb);
    b.c1 = da * bb + (1.f - da) * (1.f - bb);
    b.c2 = (1.f - da) * bb;
    b.d0 = da; b.d1 = 1.f - da;
    b.e[0] = b.c0*b.d0;
    b.e[1] = b.c0*b.d1 + b.c1*b.d0;
    b.e[2] = b.c1*b.d1 + b.c2*b.d0;
    b.e[3] = b.c2*b.d1;
    b.g = b.gb * b.gn;
    return b;
}

// conv c = a ⊛ b into slot arena (stride STR, data at +32, zero-padded):
// a width <= 28. Reads b[32 + j - i], i<28 -> idx >= 5 (front pad), <= 92 < STR.
static __device__ __forceinline__ void conv28(float* F, int dst, int a, int b,
                                              int nOut, int tid) {
    if (tid < nOut) {
        const float4* A4 = (const float4*)&F[a*K1STR + 32];
        const float*  Bp = &F[b*K1STR + 32];
        float s0 = 0.f, s1 = 0.f, s2 = 0.f, s3 = 0.f;
#pragma unroll
        for (int m = 0; m < 7; ++m) {
            const float4 av = A4[m];
            s0 += av.x * Bp[tid - 4*m];
            s1 += av.y * Bp[tid - 4*m - 1];
            s2 += av.z * Bp[tid - 4*m - 2];
            s3 += av.w * Bp[tid - 4*m - 3];
        }
        F[dst*K1STR + 32 + tid] = (s0 + s1) + (s2 + s3);
    }
}

// ---------------- K1: R = Σ_{k=0..19} A^k Ds ----------------
__global__ __launch_bounds__(TPB, 1)
void k1_kernel(const int* Lp, const float* pk, const float* __restrict__ exc,
               const float* gnp, const float* gbp, const float* bbp, const float* dap,
               float* __restrict__ R, int T) {
    __shared__ __align__(16) float Ds[DSPAN];
    __shared__ __align__(16) float F[(K1NF + 1) * K1STR];

    const Base B = mkbase(Lp, pk, gnp, gbp, bbp, dap);
    const int tid  = threadIdx.x;
    const int P0   = 2 * B.L;
    const int BACK = 19 * P0 + 64;          // even, mult of 4
    const int span = CH + BACK;
    const int b0   = blockIdx.x * CH;

    for (int i = tid; i < (K1NF + 1) * K1STR; i += TPB) F[i] = 0.f;

    // stage Ds = D_l + D_r from excitation (validated r2 formulas)
    for (int i = tid; i < span; i += TPB) {
        const int t = b0 - BACK + i;
        float v = 0.f;
        if (t >= 0 && t < T) {
            auto ex = [&](int s) -> float { return (s >= 0) ? exc[s] : 0.f; };
            v = 0.5f * ex(t - B.nDown)
              + (0.5f * B.gb) * (B.c0 * ex(t - B.L     - B.nUp)
                               + B.c1 * ex(t - B.L - 1 - B.nUp)
                               + B.c2 * ex(t - B.L - 2 - B.nUp))
              + 0.5f * ex(t - B.nUp)
              + (0.5f * B.gn) * (B.d0 * ex(t - B.L     - B.nDown)
                               + B.d1 * ex(t - B.L - 1 - B.nDown));
        }
        Ds[i] = v;
    }
    __syncthreads();
    if (tid < 4) F[1*K1STR + 32 + tid] = B.g * B.e[tid];   // seed ẽ = g·e
    __syncthreads();
    conv28(F, 2, 1, 1, 7, tid);                            // ẽ^2
    __syncthreads();
    conv28(F, 3, 1, 2, 10, tid);  conv28(F, 4, 2, 2, 13, tid);
    __syncthreads();
    conv28(F, 5, 1, 4, 16, tid);  conv28(F, 6, 2, 4, 19, tid);
    conv28(F, 7, 3, 4, 22, tid);  conv28(F, 8, 4, 4, 25, tid);
    __syncthreads();
    conv28(F, 9, 1, 8, 28, tid);  conv28(F,10, 2, 8, 31, tid);
    conv28(F,11, 3, 8, 34, tid);  conv28(F,12, 4, 8, 37, tid);
    conv28(F,13, 5, 8, 40, tid);  conv28(F,14, 6, 8, 43, tid);
    conv28(F,15, 7, 8, 46, tid);  conv28(F,16, 8, 8, 49, tid);
    __syncthreads();
    conv28(F,17, 1,16, 52, tid);  conv28(F,18, 2,16, 55, tid);
    conv28(F,19, 3,16, 58, tid);
    __syncthreads();

    // FIR: identity + 19 filters over the shared Ds window
    const int t0 = b0 + tid * SAMP;
    float a0 = Ds[BACK + tid*2], a1 = Ds[BACK + tid*2 + 1];
    const float2* W2 = (const float2*)Ds;
#pragma unroll
    for (int k = 1; k <= K1NF; ++k) {
        const int nk = 3*k + 1;
        const int np = ((nk + 2) & ~3) + 1;     // ≡ 1 (mod 4), F zero-padded
        const int Kc = (np - 1) >> 2;
        const float4* F4 = (const float4*)&F[k*K1STR + 32];
        const int pb = (BACK - k*P0 + tid*2) >> 1;
        float2 PA = W2[pb], PB = W2[pb - 1];
        for (int c = 0; c < Kc; ++c) {
            const float4 f  = F4[c];
            const float2 PC = W2[pb - 2*c - 2];
            a0 += f.x*PA.x + f.y*PB.y + f.z*PB.x + f.w*PC.y;
            a1 += f.x*PA.y + f.y*PA.x + f.z*PB.y + f.w*PB.x;
            PA = PC;
            PB = W2[pb - 2*c - 3];
        }
        const float ft = F4[Kc].x;
        a0 += ft * PA.x; a1 += ft * PA.y;
    }
    if (t0 + 1 < T)      *(float2*)(R + t0) = float2{a0, a1};
    else if (t0 < T)     R[t0] = a0;
}

// ---------------- K2: out = Σ_{j=0..9} A^{20j} R ----------------
__global__ __launch_bounds__(TPB, 1)
void k2_kernel(const int* Lp, const float* pk,
               const float* gnp, const float* gbp, const float* bbp, const float* dap,
               const float* __restrict__ R, float* __restrict__ out, int T) {
    __shared__ __align__(16) float W[K2NF][ROW2];
    __shared__ __align__(16) float ES[6 * ESTR];     // ẽ1,ẽ2,ẽ4,ẽ8,ẽ16,ẽ20
    __shared__ __align__(16) float SS[K2NF * SSTR];  // s_j = trunc(ẽ^{20j})
    __shared__ int sLo[K2NF + 1], sNp[K2NF + 1];

    const Base B = mkbase(Lp, pk, gnp, gbp, bbp, dap);
    const int tid = threadIdx.x;
    const int P0  = 2 * B.L;
    const int b0  = blockIdx.x * CH;

    for (int i = tid; i < 6*ESTR;     i += TPB) ES[i] = 0.f;
    for (int i = tid; i < K2NF*SSTR;  i += TPB) SS[i] = 0.f;

    if (tid >= 1 && tid <= K2NF) {   // truncation window for A^{20*tid}
        const float m1 = B.e[1] + 2.f*B.e[2] + 3.f*B.e[3];   // Σe = 1
        const float m2 = B.e[1] + 4.f*B.e[2] + 9.f*B.e[3];
        const float sg = sqrtf(fmaxf(m2 - m1*m1, 1e-6f));
        const int p = 20 * tid;
        const float mu = p * m1, s5 = 5.f * sg * sqrtf((float)p);
        int lo = (int)floorf(mu - s5); if (lo < 0) lo = 0;
        int hi = (int)ceilf(mu + s5);  if (hi > 3*p) hi = 3*p;
        int np = ((hi - lo + 1 + 2) & ~3) + 1;
        if (np > 141) { np = 141; lo = (int)mu - 70; if (lo < 0) lo = 0; }
        sLo[tid] = lo; sNp[tid] = np;
    }
    __syncthreads();

    // stage the 9 window rows from R (loads overlap the filter-chain build)
    for (int j = 1; j <= K2NF; ++j) {
        const int np  = sNp[j];
        const int dly = 20*j*P0 + sLo[j];
        const int w0  = b0 - dly - (np - 1);
        const int len = CH + np - 1;
        for (int i = tid; i < len; i += TPB) {
            const int s = w0 + i;
            W[j-1][8 + i] = (s >= 0 && s < T) ? R[s] : 0.f;
        }
    }
    if (tid < 4) ES[0*ESTR + 32 + tid] = B.g * B.e[tid];   // seed ẽ = g·e
    __syncthreads();
    conv28(ES, 1, 0, 0,  7, tid); __syncthreads();         // ẽ2  (ESTR==K1STR)
    conv28(ES, 2, 1, 1, 13, tid); __syncthreads();         // ẽ4
    conv28(ES, 3, 2, 2, 25, tid); __syncthreads();         // ẽ8
    conv28(ES, 4, 3, 3, 49, tid); __syncthreads();         // ẽ16
    conv28(ES, 5, 2, 4, 61, tid); __syncthreads();         // ẽ20 = ẽ4⊛ẽ16

    if (tid < sNp[1]) SS[64 + tid] = ES[5*ESTR + 32 + sLo[1] + tid];  // s1
    __syncthreads();
    for (int j = 2; j <= K2NF; ++j) {   // s_j = ẽ20 ⊛ s_{j-1}, re-truncated
        const int np = sNp[j];
        const int D  = sLo[j] - sLo[j-1];
        if (tid < np) {
            const float4* A4 = (const float4*)&ES[5*ESTR + 32];
            const float*  Bp = &SS[(j-2)*SSTR + 64];
            float s0 = 0.f, s1 = 0.f, s2 = 0.f, s3 = 0.f;
#pragma unroll
            for (int m = 0; m < 16; ++m) {   // NA=64 covers ẽ20 (61 taps)
                const float4 av = A4[m];
                s0 += av.x * Bp[tid + D - 4*m];
                s1 += av.y * Bp[tid + D - 4*m - 1];
                s2 += av.z * Bp[tid + D - 4*m - 2];
                s3 += av.w * Bp[tid + D - 4*m - 3];
            }
            SS[(j-1)*SSTR + 64 + tid] = (s0 + s1) + (s2 + s3);
        }
        __syncthreads();
    }

    // FIR: identity + 9 filters, per-filter window rows
    const int t0 = b0 + tid * SAMP;
    float a0 = (t0     < T) ? R[t0]     : 0.f;
    float a1 = (t0 + 1 < T) ? R[t0 + 1] : 0.f;
    for (int j = 1; j <= K2NF; ++j) {
        const int np = sNp[j], Kc = (np - 1) >> 2;
        const float2* W2 = (const float2*)&W[j-1][0];
        const float4* F4 = (const float4*)&SS[(j-1)*SSTR + 64];
        const int pb = (8 + (np - 1) + tid*2) >> 1;
        float2 PA = W2[pb], PB = W2[pb - 1];
#pragma unroll 2
        for (int c = 0; c < Kc; ++c) {
            const float4 f  = F4[c];
            const float2 PC = W2[pb - 2*c - 2];
            a0 += f.x*PA.x + f.y*PB.y + f.z*PB.x + f.w*PC.y;
            a1 += f.x*PA.y + f.y*PA.x + f.z*PB.y + f.w*PB.x;
            PA = PC;
            PB = W2[pb - 2*c - 3];
        }
        const float ft = F4[Kc].x;
        a0 += ft * PA.x; a1 += ft * PA.y;
    }
    if (t0 + 1 < T)      *(float2*)(out + t0) = float2{a0, a1};
    else if (t0 < T)     out[t0] = a0;
}

extern "C" void kernel_launch(void* const* d_in, const int* in_sizes, int n_in,
                              void* d_out, int out_size, void* d_ws, size_t ws_size,
                              hipStream_t stream) {
    const int*   Lp  = (const int*)  d_in[0];
    const float* pk  = (const float*)d_in[1];
    const float* exc = (const float*)d_in[2];
    const float* gn  = (const float*)d_in[3];
    const float* gb  = (const float*)d_in[4];
    const float* bb  = (const float*)d_in[5];
    const float* da  = (const float*)d_in[6];
    float* out = (float*)d_out;
    float* R   = (float*)d_ws;
    const int T = out_size;

    const int nb = (T + CH - 1) / CH;   // 188
    k1_kernel<<<nb, TPB, 0, stream>>>(Lp, pk, exc, gn, gb, bb, da, R, T);
    k2_kernel<<<nb, TPB, 0, stream>>>(Lp, pk, gn, gb, bb, da, R, out, T);
}

// Round 16
// 110.188 us; speedup vs baseline: 1.2529x; 1.2529x over previous
//
#include <hip/hip_runtime.h>

// Karplus-Strong waveguide — two-kernel fully parallel solve (traffic-engineered).
//   Validated (r1-r15): out[t] = Σ_{k=0..199} A^k (D_l + D_r)[t],
//     A = g Z^{2L} e,  e = c⊛d (4 taps, Σe = 1),  g = gb·gn.
//   Factorization (covers k=0..209 ⊇ 0..199; A^k ≡ 0 on [0,T) for k ≥ 200):
//     out = (Σ_{k<14} A^k) · (Σ_{j<15} A^{14j}) Ds
//   K1: stages exc ONCE into LDS (1 read/float), computes Ds in-LDS (7 LDS reads
//       not 7 global reads — r15's 73MB overfetch fix), builds ẽ^k = g^k e^k
//       k=1..13 in-block, applies 13-filter FIR over the shared Ds window.
//   K2: Σ_j A^{14j}, 14 filters ẽ^{14j} truncated ±5σ (Gaussian; analytic mu,σ),
//       built by ẽ14-chain; per-filter LDS window rows from R.
// FIR inner loop: float2-rolling (validated r15): 2×ds_read_b64 + 1×ds_read_b128
// per 8 FMAs.

#define TPB   512
#define SAMP  2
#define CH    (TPB*SAMP)     // 1024
#define P0M   512            // max 2L (L<=256)
#define BACKM (13*P0M + 64)  // 6720
#define EXMM  520
#define ESPM  (CH + BACKM + EXMM + 8)   // 8272
#define DSPM  (CH + BACKM + 8)          // 7752
#define FSTR  96             // filter slot: 32 front pad + 64 data
#define K2NF  14
#define NPCAP 133            // K2 truncated taps cap (<=133; actual ~115)
#define ROW2  1160           // CH + NPCAP + pad
#define SSTR  256            // s_j slot: 64 front pad + 192 data

struct Base {
    int L, nUp, nDown;
    float gb, gn, g;
    float c0, c1, c2, d0, d1;
    float e[4];
};

static __device__ __forceinline__ Base mkbase(const int* Lp, const float* pk,
        const float* gnp, const float* gbp, const float* bbp, const float* dap) {
    Base b;
    b.L = Lp[0];
    b.gn = gnp[0]; b.gb = gbp[0];
    const float bb = bbp[0], da = dap[0];
    b.nUp   = (int)rintf((float)b.L * pk[0]);   // round-half-even == jnp.round
    b.nDown = b.L - b.nUp;
    b.c0 = da * (1.f - bb);
    b.c1 = da * bb + (1.f - da) * (1.f - bb);
    b.c2 = (1.f - da) * bb;
    b.d0 = da; b.d1 = 1.f - da;
    b.e[0] = b.c0*b.d0;
    b.e[1] = b.c0*b.d1 + b.c1*b.d0;
    b.e[2] = b.c1*b.d1 + b.c2*b.d0;
    b.e[3] = b.c2*b.d1;
    b.g = b.gb * b.gn;
    return b;
}

// C[m] = Σ_i A[i]·Bp[m + D - i], i < 4*NA4.  A 16B-aligned, zero-padded;
// Bp reads below 0 / past data must land in zero pads.
template<int NA4>
static __device__ __forceinline__ void convA(const float* A, const float* Bp,
                                             float* C, int nOut, int D, int tid) {
    if (tid < nOut) {
        const float4* A4 = (const float4*)A;
        float s0 = 0.f, s1 = 0.f, s2 = 0.f, s3 = 0.f;
#pragma unroll
        for (int m = 0; m < NA4; ++m) {
            const float4 av = A4[m];
            s0 += av.x * Bp[tid + D - 4*m];
            s1 += av.y * Bp[tid + D - 4*m - 1];
            s2 += av.z * Bp[tid + D - 4*m - 2];
            s3 += av.w * Bp[tid + D - 4*m - 3];
        }
        C[tid] = (s0 + s1) + (s2 + s3);
    }
}

// rolling float2 FIR: acc over taps j=0..np-1 (np ≡ 1 mod 4), filter zero-padded
static __device__ __forceinline__ void fir2(const float2* W2, int pb,
                                            const float4* F4, int np,
                                            float& a0, float& a1) {
    const int Kc = (np - 1) >> 2;
    float2 PA = W2[pb], PB = W2[pb - 1];
    for (int c = 0; c < Kc; ++c) {
        const float4 f  = F4[c];
        const float2 PC = W2[pb - 2*c - 2];
        a0 += f.x*PA.x + f.y*PB.y + f.z*PB.x + f.w*PC.y;
        a1 += f.x*PA.y + f.y*PA.x + f.z*PB.y + f.w*PB.x;
        PA = PC;
        PB = W2[pb - 2*c - 3];
    }
    const float ft = F4[Kc].x;
    a0 += ft * PA.x;
    a1 += ft * PA.y;
}

// ---------------- K1: R = Σ_{k=0..13} A^k Ds ----------------
__global__ __launch_bounds__(TPB, 1)
void k1_kernel(const int* Lp, const float* pk, const float* __restrict__ exc,
               const float* gnp, const float* gbp, const float* bbp, const float* dap,
               float* __restrict__ R, int T) {
    __shared__ __align__(16) float EX[ESPM];
    __shared__ __align__(16) float DS[DSPM];
    __shared__ __align__(16) float F[14 * FSTR];

    const Base B = mkbase(Lp, pk, gnp, gbp, bbp, dap);
    const int tid  = threadIdx.x;
    const int P0   = 2 * B.L;
    const int BACK = 13 * P0 + 64;
    const int mx   = (B.nUp > B.nDown) ? B.nUp : B.nDown;
    const int EXM  = (B.L + mx + 2 + 7) & ~3;
    const int esp  = CH + BACK + EXM;
    const int dsp  = CH + BACK;
    const int b0   = blockIdx.x * CH;

    for (int i = tid; i < 14 * FSTR; i += TPB) F[i] = 0.f;
    // stage exc window ONCE (coalesced, 1 read/float)
    for (int i = tid; i < esp; i += TPB) {
        const int s = b0 - BACK - EXM + i;
        EX[i] = (s >= 0 && s < T) ? exc[s] : 0.f;
    }
    __syncthreads();
    // Ds from LDS (validated r2 formulas; t<0 auto-zero via zero-filled EX)
    for (int i = tid; i < dsp; i += TPB) {
        const float* Ep = &EX[i + EXM];
        DS[i] = 0.5f * (Ep[-B.nDown] + Ep[-B.nUp])
              + (0.5f * B.gb) * (B.c0 * Ep[-B.L     - B.nUp]
                               + B.c1 * Ep[-B.L - 1 - B.nUp]
                               + B.c2 * Ep[-B.L - 2 - B.nUp])
              + (0.5f * B.gn) * (B.d0 * Ep[-B.L     - B.nDown]
                               + B.d1 * Ep[-B.L - 1 - B.nDown]);
    }
    if (tid < 4) F[1*FSTR + 32 + tid] = B.g * B.e[tid];   // seed ẽ = g·e
    __syncthreads();
    // ẽ^k build tree (conv28: a-width <= 28; all a-operands <= 16 taps)
    auto C28 = [&](int dst, int a, int b, int n) {
        convA<7>(&F[a*FSTR + 32], &F[b*FSTR + 32], &F[dst*FSTR + 32], n, 0, tid);
    };
    C28(2, 1, 1, 7);  __syncthreads();
    C28(3, 1, 2, 10); C28(4, 2, 2, 13); __syncthreads();
    C28(5, 1, 4, 16); C28(6, 2, 4, 19); C28(7, 3, 4, 22); C28(8, 4, 4, 25);
    __syncthreads();
    C28(9, 1, 8, 28); C28(10, 2, 8, 31); C28(11, 3, 8, 34); C28(12, 4, 8, 37);
    C28(13, 5, 8, 40);
    __syncthreads();

    // FIR: identity + 13 filters over the shared Ds window
    const int t0 = b0 + tid * SAMP;
    float a0 = DS[BACK + tid*2], a1 = DS[BACK + tid*2 + 1];
    const float2* W2 = (const float2*)DS;
    for (int k = 1; k <= 13; ++k) {
        const int nk = 3*k + 1;
        const int np = ((nk + 2) & ~3) + 1;
        const int pb = ((BACK - k*P0) >> 1) + tid;
        fir2(W2, pb, (const float4*)&F[k*FSTR + 32], np, a0, a1);
    }
    if (t0 + 1 < T)  *(float2*)(R + t0) = float2{a0, a1};
    else if (t0 < T) R[t0] = a0;
}

// ---------------- K2: out = Σ_{j=0..14} A^{14j} R ----------------
__global__ __launch_bounds__(TPB, 1)
void k2_kernel(const int* Lp, const float* pk,
               const float* gnp, const float* gbp, const float* bbp, const float* dap,
               const float* __restrict__ R, float* __restrict__ out, int T) {
    __shared__ __align__(16) float W[K2NF][ROW2];
    __shared__ __align__(16) float ES[6 * FSTR];      // ẽ1,ẽ2,ẽ3,ẽ4,ẽ7,ẽ14
    __shared__ __align__(16) float SS[K2NF * SSTR];   // s_j = trunc(ẽ^{14j})
    __shared__ int sLo[K2NF + 1], sNp[K2NF + 1];

    const Base B = mkbase(Lp, pk, gnp, gbp, bbp, dap);
    const int tid = threadIdx.x;
    const int P0  = 2 * B.L;
    const int b0  = blockIdx.x * CH;

    for (int i = tid; i < 6 * FSTR;    i += TPB) ES[i] = 0.f;
    for (int i = tid; i < K2NF * SSTR; i += TPB) SS[i] = 0.f;

    if (tid >= 1 && tid <= K2NF) {   // truncation window for A^{14*tid}
        const float m1 = B.e[1] + 2.f*B.e[2] + 3.f*B.e[3];   // Σe = 1
        const float m2 = B.e[1] + 4.f*B.e[2] + 9.f*B.e[3];
        const float sg = sqrtf(fmaxf(m2 - m1*m1, 1e-6f));
        const int p = 14 * tid;
        const float mu = p * m1, s5 = 5.f * sg * sqrtf((float)p);
        int lo = (int)floorf(mu - s5); if (lo < 0) lo = 0;
        int hi = (int)ceilf(mu + s5);  if (hi > 3*p) hi = 3*p;
        int np = ((hi - lo + 1 + 2) & ~3) + 1;
        if (np > NPCAP) { np = NPCAP; lo = (int)mu - NPCAP/2; if (lo < 0) lo = 0; }
        sLo[tid] = lo; sNp[tid] = np;
    }
    if (tid < 4) ES[0*FSTR + 32 + tid] = B.g * B.e[tid];   // seed ẽ = g·e
    __syncthreads();

    // stage the 14 window rows from R (delayed, per-filter)
    bool on[K2NF + 1];
    for (int j = 1; j <= K2NF; ++j) {
        const int np  = sNp[j];
        const int dly = 14*j*P0 + sLo[j];
        on[j] = (b0 + CH - 1 - dly) >= 0;
        if (!on[j]) continue;
        const int w0  = b0 - dly - (np - 1);
        const int len = CH + np - 1;
        for (int i = tid; i < len; i += TPB) {
            const int s = w0 + i;
            W[j-1][8 + i] = (s >= 0 && s < T) ? R[s] : 0.f;
        }
    }
    auto C28 = [&](int dst, int a, int b, int n) {
        convA<7>(&ES[a*FSTR + 32], &ES[b*FSTR + 32], &ES[dst*FSTR + 32], n, 0, tid);
    };
    C28(1, 0, 0, 7);  __syncthreads();                 // ẽ2
    C28(2, 0, 1, 10); C28(3, 1, 1, 13); __syncthreads();   // ẽ3, ẽ4
    C28(4, 2, 3, 22); __syncthreads();                 // ẽ7 = ẽ3⊛ẽ4
    C28(5, 4, 4, 43); __syncthreads();                 // ẽ14 = ẽ7⊛ẽ7

    if (tid < sNp[1]) SS[64 + tid] = ES[5*FSTR + 32 + sLo[1] + tid];   // s1
    __syncthreads();
    for (int j = 2; j <= K2NF; ++j) {   // s_j = ẽ14 ⊛ s_{j-1}, re-truncated
        convA<11>(&ES[5*FSTR + 32], &SS[(j-2)*SSTR + 64],
                  &SS[(j-1)*SSTR + 64], sNp[j], sLo[j] - sLo[j-1], tid);
        __syncthreads();
    }

    // FIR: identity + 14 filters (per-filter rows)
    const int t0 = b0 + tid * SAMP;
    float a0 = (t0     < T) ? R[t0]     : 0.f;
    float a1 = (t0 + 1 < T) ? R[t0 + 1] : 0.f;
    for (int j = 1; j <= K2NF; ++j) {
        if (!on[j]) continue;
        const int np = sNp[j];
        const int pb = ((8 + np - 1) >> 1) + tid;
        fir2((const float2*)&W[j-1][0], pb,
             (const float4*)&SS[(j-1)*SSTR + 64], np, a0, a1);
    }
    if (t0 + 1 < T)  *(float2*)(out + t0) = float2{a0, a1};
    else if (t0 < T) out[t0] = a0;
}

extern "C" void kernel_launch(void* const* d_in, const int* in_sizes, int n_in,
                              void* d_out, int out_size, void* d_ws, size_t ws_size,
                              hipStream_t stream) {
    const int*   Lp  = (const int*)  d_in[0];
    const float* pk  = (const float*)d_in[1];
    const float* exc = (const float*)d_in[2];
    const float* gn  = (const float*)d_in[3];
    const float* gb  = (const float*)d_in[4];
    const float* bb  = (const float*)d_in[5];
    const float* da  = (const float*)d_in[6];
    float* out = (float*)d_out;
    float* R   = (float*)d_ws;
    const int T = out_size;

    const int nb = (T + CH - 1) / CH;   // 94
    k1_kernel<<<nb, TPB, 0, stream>>>(Lp, pk, exc, gn, gb, bb, da, R, T);
    k2_kernel<<<nb, TPB, 0, stream>>>(Lp, pk, gn, gb, bb, da, R, out, T);
}